// Round 1
// baseline (184.946 us; speedup 1.0000x reference)
//
#include <hip/hip_runtime.h>
#include <math.h>
#include <stdint.h>

#define NUMCH 65
#define THREADS 256
#define WAVES 4
#define NTILE 4
#define CTILE 1024
#define TILE_T (NTILE * CTILE)   // 4096
#define NGRP 24                  // grid 24*8*4 = 768 = exactly 3 blocks/CU resident
#define PLEN 896                 // max piece len -> nc <= 58
#define MAXP 224

#define XDW_MAX 2528              // packed x-plane dwords (max EN = 16*58+4096+32 = 5056 el / 2)
#define XPHYS 2840                // swizzled plane size: SW(2527)=2839 -> 2840 (16B-aligned)
#define WB_MAX 976                // 16*58+48
#define BUFDW (2 * XPHYS + WB_MAX)   // 6656 dwords per buffer
#define SMEM_DW (2 * BUFDW)          // 13312 dwords = 52 KiB -> 3 blocks/CU
#define NXP 10                    // ceil(XDW_MAX / THREADS)
#define NWB 4                     // ceil(WB_MAX / THREADS)

#define SW(d) ((d) + ((((d) >> 5)) << 2))

struct PTab {
  short c[MAXP], ka[MAXP], len[MAXP], nc[MAXP];
  int start[NGRP + 1];
};

typedef short bf16x8 __attribute__((ext_vector_type(8)));
typedef float f32x16 __attribute__((ext_vector_type(16)));

__global__ void zero_kernel(float* __restrict__ out, int n)
{
  int i = blockIdx.x * blockDim.x + threadIdx.x;
  if (i < n) out[i] = 0.0f;
}

// round-to-nearest-even fp32 -> bf16 bits
__device__ __forceinline__ uint32_t f2bf(float f) {
  uint32_t u = __float_as_uint(f);
  return (u + 0x7FFFu + ((u >> 16) & 1u)) >> 16;
}
// h = bf16(v), l = bf16(v - h)
__device__ __forceinline__ void splithl(float v, uint32_t& h, uint32_t& l) {
  h = f2bf(v);
  l = f2bf(v - __uint_as_float(h << 16));
}
__device__ __forceinline__ uint32_t packhl(float v) {
  uint32_t h, l;
  splithl(v, h, l);
  return h | (l << 16);
}

// out[b,t] += (1/fs) * sum_c sum_k w[c,k] * x[b,c, t + off_c + k]
// Per chunk ci, tile tau:  C[i][j] += sum_kk A[i][kk]*B[kk][j]
//   A[i][kk] = w[ka+16ci+kk-i] (Toeplitz band), B[kk][j] = x[X0 + 1024*tau + 32j + 16ci + kk]
//   C[i][j] -> out[t0 + 1024*tau + 32j + i]
// Piece pipeline: (A) prefetch piece pi+1 globals into regs, (B) compute pi from
// LDS buf[cur], (C) hl-split + write buf[cur^1], one barrier. Load latency and
// split VALU overlap MFMA of other waves.
__global__ __launch_bounds__(THREADS, 3)
void conv_mfma_kernel(const float* __restrict__ inp, const float* __restrict__ w,
                      const int* __restrict__ gidx, const int* __restrict__ fsp,
                      float* __restrict__ out, PTab P, int B, int T, int K)
{
  __shared__ __align__(16) uint32_t smem[SMEM_DW];

  const int g = blockIdx.x, tile4 = blockIdx.y, b = blockIdx.z;
  const int tid = threadIdx.x;
  const int lane = tid & 63;
  const int wv = tid >> 6;
  const int col = lane & 31;
  const int half = lane >> 5;
  const int t0 = tile4 * TILE_T;

  f32x16 acc[NTILE];
  #pragma unroll
  for (int t = 0; t < NTILE; ++t)
    #pragma unroll
    for (int i = 0; i < 16; ++i) acc[t][i] = 0.0f;

  const int s0 = P.start[g], s1 = P.start[g + 1];

  // ---- prologue: stage piece s0 directly into buffer 0 ----
  if (s0 < s1) {
    const int c   = P.c[s0];
    const int ka  = P.ka[s0];
    const int len = P.len[s0];
    const int nc0 = P.nc[s0];
    const int XDWn = (16 * nc0 + TILE_T + 32) >> 1;
    const int WB  = 16 * nc0 + 48;
    const int start_c = gidx[(size_t)c * T];
    const int X0 = t0 + start_c - (K - 1) + ka;
    const float* __restrict__ xc = inp + ((size_t)b * (2 * NUMCH) + c) * T;
    const float* __restrict__ wc = w + (size_t)c * K;
    for (int d = tid; d < XDWn; d += THREADS) {
      const int gi0 = X0 + 2 * d, gi1 = gi0 + 1;
      const float v0 = (gi0 >= 0 && gi0 < T) ? xc[gi0] : 0.0f;
      const float v1 = (gi1 >= 0 && gi1 < T) ? xc[gi1] : 0.0f;
      uint32_t h0, l0, h1, l1;
      splithl(v0, h0, l0);
      splithl(v1, h1, l1);
      const int pd = SW(d);
      smem[pd] = h0 | (h1 << 16);
      smem[XPHYS + pd] = l0 | (l1 << 16);
    }
    for (int d = tid; d < WB; d += THREADS) {
      const int k = ka + d - 32;
      const float v = (d >= 32 && k < ka + len) ? wc[k] : 0.0f;
      smem[2 * XPHYS + d] = packhl(v);
    }
  }
  __syncthreads();

  int cur = 0;
  for (int pi = s0; pi < s1; ++pi) {
    const int nc = P.nc[pi];

    // ---- phase A: issue global loads for piece pi+1 into registers ----
    float xv0[NXP], xv1[NXP], wvv[NWB];
    int XDWn2 = 0, WB2 = 0;
    const bool hasNext = (pi + 1 < s1);
    if (hasNext) {
      const int c2   = P.c[pi + 1];
      const int ka2  = P.ka[pi + 1];
      const int len2 = P.len[pi + 1];
      const int nc2  = P.nc[pi + 1];
      XDWn2 = (16 * nc2 + TILE_T + 32) >> 1;
      WB2   = 16 * nc2 + 48;
      const int start_c2 = gidx[(size_t)c2 * T];
      const int X0_2 = t0 + start_c2 - (K - 1) + ka2;
      const float* __restrict__ xc2 = inp + ((size_t)b * (2 * NUMCH) + c2) * T;
      const float* __restrict__ wc2 = w + (size_t)c2 * K;
      #pragma unroll
      for (int j = 0; j < NXP; ++j) {
        const int d = tid + j * THREADS;
        const int gi0 = X0_2 + 2 * d, gi1 = gi0 + 1;
        xv0[j] = (d < XDWn2 && gi0 >= 0 && gi0 < T) ? xc2[gi0] : 0.0f;
        xv1[j] = (d < XDWn2 && gi1 >= 0 && gi1 < T) ? xc2[gi1] : 0.0f;
      }
      #pragma unroll
      for (int j = 0; j < NWB; ++j) {
        const int dd = tid + j * THREADS;
        const int k = ka2 + dd - 32;
        wvv[j] = (dd < WB2 && dd >= 32 && k < ka2 + len2) ? wc2[k] : 0.0f;
      }
    }

    // ---- phase B: compute piece pi from buf[cur] ----
    {
      const uint32_t* __restrict__ xh = smem + cur * BUFDW;
      const uint32_t* __restrict__ xl = xh + XPHYS;
      const uint32_t* __restrict__ wband = xh + 2 * XPHYS;

      for (int ci = wv; ci < nc; ci += WAVES) {
        const int abase = 32 + 16 * ci + 8 * half - col;
        uint32_t ad[8];
        #pragma unroll
        for (int j = 0; j < 8; ++j) ad[j] = wband[abase + j];
        union AU { uint32_t u[4]; bf16x8 v; } Ah, Al;
        #pragma unroll
        for (int j = 0; j < 4; ++j) {
          const uint32_t a0 = ad[2 * j], a1 = ad[2 * j + 1];
          Ah.u[j] = (a0 & 0xFFFFu) | (a1 << 16);
          Al.u[j] = (a0 >> 16) | (a1 & 0xFFFF0000u);
        }
        const int dbase = 16 * col + 4 * half + 8 * ci;
        #pragma unroll
        for (int tau = 0; tau < NTILE; ++tau) {
          const int d = 512 * tau + dbase;
          const int pd = SW(d);
          union BU { uint4 q; bf16x8 v; } Bh, Bl;
          Bh.q = *(const uint4*)&xh[pd];
          Bl.q = *(const uint4*)&xl[pd];
          acc[tau] = __builtin_amdgcn_mfma_f32_32x32x16_bf16(Ah.v, Bh.v, acc[tau], 0, 0, 0);
          acc[tau] = __builtin_amdgcn_mfma_f32_32x32x16_bf16(Ah.v, Bl.v, acc[tau], 0, 0, 0);
          acc[tau] = __builtin_amdgcn_mfma_f32_32x32x16_bf16(Al.v, Bh.v, acc[tau], 0, 0, 0);
        }
      }
    }

    // ---- phase C: split + write piece pi+1 into buf[cur^1] ----
    if (hasNext) {
      uint32_t* __restrict__ yh = smem + (cur ^ 1) * BUFDW;
      uint32_t* __restrict__ yl = yh + XPHYS;
      uint32_t* __restrict__ yw = yh + 2 * XPHYS;
      #pragma unroll
      for (int j = 0; j < NXP; ++j) {
        const int d = tid + j * THREADS;
        if (d < XDWn2) {
          uint32_t h0, l0, h1, l1;
          splithl(xv0[j], h0, l0);
          splithl(xv1[j], h1, l1);
          const int pd = SW(d);
          yh[pd] = h0 | (h1 << 16);
          yl[pd] = l0 | (l1 << 16);
        }
      }
      #pragma unroll
      for (int j = 0; j < NWB; ++j) {
        const int dd = tid + j * THREADS;
        if (dd < WB2) yw[dd] = packhl(wvv[j]);
      }
    }
    __syncthreads();
    cur ^= 1;
  }

  // epilogue: per tile, cross-wave LDS reduce + one atomicAdd per output.
  // Rotation swizzle 32*col + ((row+col)&31): conflict-free writes and reads.
  const float inv_fs = 1.0f / (float)fsp[0];
  for (int tau = 0; tau < NTILE; ++tau) {
    #pragma unroll
    for (int r = 0; r < 16; ++r) {
      const int row = (r & 3) + 8 * (r >> 2) + 4 * half;   // verified C/D layout
      smem[wv * CTILE + 32 * col + ((row + col) & 31)] = __float_as_uint(acc[tau][r]);
    }
    __syncthreads();
    for (int i = tid; i < CTILE; i += THREADS) {
      const int q = i >> 5, s = i & 31;
      const int pidx = 32 * q + ((s + q) & 31);
      float sum = __uint_as_float(smem[pidx]) +
                  __uint_as_float(smem[CTILE + pidx]) +
                  __uint_as_float(smem[2 * CTILE + pidx]) +
                  __uint_as_float(smem[3 * CTILE + pidx]);
      atomicAdd(&out[(size_t)b * T + t0 + tau * CTILE + i], sum * inv_fs);
    }
    __syncthreads();
  }
}

extern "C" void kernel_launch(void* const* d_in, const int* in_sizes, int n_in,
                              void* d_out, int out_size, void* d_ws, size_t ws_size,
                              hipStream_t stream)
{
  const float* inp = (const float*)d_in[0];
  const float* wgt = (const float*)d_in[1];
  const int* gidx  = (const int*)d_in[2];
  const int* fsp   = (const int*)d_in[3];
  float* out = (float*)d_out;

  const int K = in_sizes[1] / NUMCH;
  const int T = in_sizes[2] / NUMCH;
  const int B = in_sizes[0] / (2 * NUMCH * T);

  // ---- host-side piece construction (analytic gammatone lengths, 48-tap margin) ----
  const double a = pow(10.0, 1.0 / 32.0);
  int pC[MAXP], pKa[MAXP], pLen[MAXP], pNc[MAXP];
  double pW[MAXP];
  int np_ = 0;
  for (int c = 0; c < NUMCH; ++c) {
    int gl = (int)ceil((K / 10.0) * pow(a, 32.0 - c) - 1e-9);
    if (gl > K) gl = K;
    int k0 = K - gl - 48; if (k0 < 0) k0 = 0;
    const int len = K - k0;
    const int npc = (len + PLEN - 1) / PLEN;
    int plen = (len + npc - 1) / npc;
    plen = (plen + 15) & ~15;
    for (int i = 0; i < npc && np_ < MAXP; ++i) {
      const int kai = k0 + i * plen;
      if (kai >= K) break;
      const int li = (K - kai < plen) ? (K - kai) : plen;
      pC[np_] = c; pKa[np_] = kai; pLen[np_] = li;
      pNc[np_] = (li + 15) / 16 + 2;
      pW[np_] = (double)pNc[np_] + 4.0;   // chunk work + (pipelined) staging overhead
      ++np_;
    }
  }
  // sort pieces by descending work
  for (int i = 1; i < np_; ++i) {
    int c = pC[i], ka = pKa[i], ln = pLen[i], nc = pNc[i];
    double wv = pW[i];
    int j = i - 1;
    while (j >= 0 && pW[j] < wv) {
      pC[j+1]=pC[j]; pKa[j+1]=pKa[j]; pLen[j+1]=pLen[j]; pNc[j+1]=pNc[j]; pW[j+1]=pW[j]; --j;
    }
    pC[j+1]=c; pKa[j+1]=ka; pLen[j+1]=ln; pNc[j+1]=nc; pW[j+1]=wv;
  }
  // greedy LPT into NGRP groups
  double gsum[NGRP]; int gcnt[NGRP];
  static int glist[NGRP][MAXP];
  for (int g = 0; g < NGRP; ++g) { gsum[g] = 0.0; gcnt[g] = 0; }
  for (int i = 0; i < np_; ++i) {
    int best = 0;
    for (int g = 1; g < NGRP; ++g) if (gsum[g] < gsum[best]) best = g;
    glist[best][gcnt[best]++] = i;
    gsum[best] += pW[i];
  }
  PTab P;
  int p = 0;
  P.start[0] = 0;
  for (int g = 0; g < NGRP; ++g) {
    for (int i = 0; i < gcnt[g]; ++i) {
      const int id = glist[g][i];
      P.c[p] = (short)pC[id]; P.ka[p] = (short)pKa[id];
      P.len[p] = (short)pLen[id]; P.nc[p] = (short)pNc[id];
      ++p;
    }
    P.start[g + 1] = p;
  }
  for (int i = p; i < MAXP; ++i) { P.c[i] = 0; P.ka[i] = 0; P.len[i] = 0; P.nc[i] = 0; }

  zero_kernel<<<(out_size + 255) / 256, 256, 0, stream>>>(out, out_size);
  dim3 grid(NGRP, T / TILE_T, B);
  conv_mfma_kernel<<<grid, THREADS, 0, stream>>>(inp, wgt, gidx, fsp, out, P, B, T, K);
}